// Round 1
// baseline (209.738 us; speedup 1.0000x reference)
//
#include <hip/hip_runtime.h>

// Problem constants (from reference setup_inputs)
//   N=4096 rows, T=16 steps, D=700 input dim, C=128 channels, NC=20 classes
// Output layout (f32, concat): out0 [4096,20] | features [16,4096,128] | attended [16,4096,128]

// ---------------------------------------------------------------------------
// Transpose the three 128x128 weight matrices so spike-gathers read rows
// coalesced: WT[j*128+c] = W[c*128+j]
// ---------------------------------------------------------------------------
__global__ void k_transpose(const float* __restrict__ Wr, const float* __restrict__ W2,
                            const float* __restrict__ Wp, float* __restrict__ WrT,
                            float* __restrict__ W2T, float* __restrict__ WpT) {
  int idx = blockIdx.x * blockDim.x + threadIdx.x;
  if (idx >= 3 * 16384) return;
  int sel = idx >> 14;
  int r = idx & 16383;
  int j = r >> 7, c = r & 127;
  const float* src = (sel == 0) ? Wr : (sel == 1) ? W2 : Wp;
  float* dst = (sel == 0) ? WrT : (sel == 1) ? W2T : WpT;
  dst[r] = src[c * 128 + j];
}

// ---------------------------------------------------------------------------
// GEMM1: XW[t*4096+n][c] = x[n,t,:] . W_in[c,:] + b_in[c] + b_rec[c]
// M=65536, K=700, N=128.  128x128 block tile, 8x8 per thread, K-tile 32.
// ---------------------------------------------------------------------------
__global__ __launch_bounds__(256) void k_gemm_xw(
    const float* __restrict__ x, const float* __restrict__ Win,
    const float* __restrict__ b_in, const float* __restrict__ b_rec,
    float* __restrict__ XW) {
  __shared__ float As[32][128];
  __shared__ float Bs[32][128];
  const int tid = threadIdx.x;
  const int m0 = blockIdx.x * 128;
  const int ty = tid >> 4, tx = tid & 15;

  float acc[8][8];
#pragma unroll
  for (int i = 0; i < 8; ++i)
#pragma unroll
    for (int j = 0; j < 8; ++j) acc[i][j] = 0.f;

  // staging assignment: thread -> row (tid>>1), 16-float chunk ((tid&1)*16)
  const int sr = tid >> 1;
  const int skb = (tid & 1) * 16;
  const int m = m0 + sr;
  const int tt = m >> 12;        // t
  const int nn = m & 4095;       // n
  const float* arow = x + (size_t)(nn * 16 + tt) * 700;
  const float* brow = Win + (size_t)sr * 700;  // sr is the output channel here

  for (int k0 = 0; k0 < 700; k0 += 32) {
    __syncthreads();
#pragma unroll
    for (int j = 0; j < 4; ++j) {
      int kl = skb + j * 4;
      int k = k0 + kl;
      float4 av, bv;
      if (k + 3 < 700) {  // 700 % 4 == 0, so chunk-level guard is exact
        av = *reinterpret_cast<const float4*>(arow + k);
        bv = *reinterpret_cast<const float4*>(brow + k);
      } else {
        av = make_float4(0.f, 0.f, 0.f, 0.f);
        bv = make_float4(0.f, 0.f, 0.f, 0.f);
      }
      As[kl + 0][sr] = av.x; As[kl + 1][sr] = av.y;
      As[kl + 2][sr] = av.z; As[kl + 3][sr] = av.w;
      Bs[kl + 0][sr] = bv.x; Bs[kl + 1][sr] = bv.y;
      Bs[kl + 2][sr] = bv.z; Bs[kl + 3][sr] = bv.w;
    }
    __syncthreads();
#pragma unroll
    for (int k = 0; k < 32; ++k) {
      float4 a0 = *reinterpret_cast<const float4*>(&As[k][ty * 4]);
      float4 a1 = *reinterpret_cast<const float4*>(&As[k][ty * 4 + 64]);
      float4 b0 = *reinterpret_cast<const float4*>(&Bs[k][tx * 4]);
      float4 b1 = *reinterpret_cast<const float4*>(&Bs[k][tx * 4 + 64]);
      float av[8] = {a0.x, a0.y, a0.z, a0.w, a1.x, a1.y, a1.z, a1.w};
      float bv[8] = {b0.x, b0.y, b0.z, b0.w, b1.x, b1.y, b1.z, b1.w};
#pragma unroll
      for (int i = 0; i < 8; ++i)
#pragma unroll
        for (int j = 0; j < 8; ++j) acc[i][j] += av[i] * bv[j];
    }
  }

  float bias[8];
#pragma unroll
  for (int j = 0; j < 8; ++j) {
    int col = (j < 4) ? (tx * 4 + j) : (tx * 4 + 64 + (j - 4));
    bias[j] = b_in[col] + b_rec[col];
  }
#pragma unroll
  for (int i = 0; i < 8; ++i) {
    int row = m0 + ty * 4 + (i & 3) + ((i >= 4) ? 64 : 0);
    float4 v0 = make_float4(acc[i][0] + bias[0], acc[i][1] + bias[1],
                            acc[i][2] + bias[2], acc[i][3] + bias[3]);
    float4 v1 = make_float4(acc[i][4] + bias[4], acc[i][5] + bias[5],
                            acc[i][6] + bias[6], acc[i][7] + bias[7]);
    *reinterpret_cast<float4*>(XW + (size_t)row * 128 + tx * 4) = v0;
    *reinterpret_cast<float4*>(XW + (size_t)row * 128 + 64 + tx * 4) = v1;
  }
}

// ---------------------------------------------------------------------------
// Phase A: per-row recurrent LIF scan over T=16.
// Block = one sample row n (128 threads = channels). Spike matmuls are
// ballot-mask gathers of WT rows (exact; fast when sparse).
// Also emits mean over channels (per t) and mean over t (per n,c).
// ---------------------------------------------------------------------------
__global__ __launch_bounds__(128) void k_phaseA(
    const float* __restrict__ XW, const float* __restrict__ WrT,
    const float* __restrict__ W2T, const float* __restrict__ b2,
    float* __restrict__ features, float* __restrict__ mean_ch,
    float* __restrict__ mean0) {
  const int n = blockIdx.x;
  const int c = threadIdx.x;
  const int wv = c >> 6, lane = c & 63;
  __shared__ unsigned long long smask[2];
  __shared__ float red[2];
  if (c < 2) smask[c] = 0ull;
  float v1 = 0.f, v2 = 0.f, fsum = 0.f;
  const float b2c = b2[c];
  __syncthreads();
  for (int t = 0; t < 16; ++t) {
    float inp = XW[(size_t)((t << 12) | n) * 128 + c];
    unsigned long long p0 = smask[0], p1 = smask[1];   // spikes_last (uniform)
    while (p0) { int j = __builtin_ctzll(p0); p0 &= p0 - 1; inp += WrT[j * 128 + c]; }
    while (p1) { int j = __builtin_ctzll(p1); p1 &= p1 - 1; inp += WrT[(64 + j) * 128 + c]; }
    v1 = v1 + (inp - v1) * 0.5f;            // decay_input=True, TAU=2
    bool s1 = (v1 - 1.0f) >= 0.f;           // spike(v - VTH)
    v1 = s1 ? 0.f : v1;                     // hard reset
    __syncthreads();                        // all done reading old smask
    unsigned long long bm = __ballot((int)s1);
    if (lane == 0) smask[wv] = bm;
    __syncthreads();
    float x2 = b2c;
    unsigned long long q0 = smask[0], q1 = smask[1];
    while (q0) { int j = __builtin_ctzll(q0); q0 &= q0 - 1; x2 += W2T[j * 128 + c]; }
    while (q1) { int j = __builtin_ctzll(q1); q1 &= q1 - 1; x2 += W2T[(64 + j) * 128 + c]; }
    v2 = v2 + (x2 - v2) * 0.5f;
    bool f = (v2 - 1.0f) >= 0.f;
    v2 = f ? 0.f : v2;
    float ff = f ? 1.f : 0.f;
    features[(size_t)((t << 12) | n) * 128 + c] = ff;
    fsum += ff;
    // mean over channels for this (t, n)
    float rs = ff;
    for (int off = 32; off > 0; off >>= 1) rs += __shfl_down(rs, off);
    if (lane == 0) red[wv] = rs;
    __syncthreads();
    if (c == 0) mean_ch[t * 4096 + n] = (red[0] + red[1]) * (1.f / 128.f);
    // smask now holds s1 = spikes_last for the next step
  }
  mean0[n * 128 + c] = fsum * (1.f / 16.f);
}

// ---------------------------------------------------------------------------
// Attention maps: SAME-pad width-3 correlations + sigmoid.
// t_att[t][n] over the T axis of mean_ch; c_att[n][c] over the C axis of mean0.
// ---------------------------------------------------------------------------
__global__ void k_atts(const float* __restrict__ mean_ch, const float* __restrict__ mean0,
                       const float* __restrict__ k_t, const float* __restrict__ k_c,
                       float* __restrict__ t_att, float* __restrict__ c_att) {
  int idx = blockIdx.x * blockDim.x + threadIdx.x;
  if (idx < 16 * 4096) {
    int ti = idx >> 12, n = idx & 4095;
    float acc = 0.f;
#pragma unroll
    for (int j = 0; j < 3; ++j) {
      int tt = ti - 1 + j;
      if (tt >= 0 && tt < 16) acc += k_t[j] * mean_ch[tt * 4096 + n];
    }
    t_att[idx] = 1.f / (1.f + expf(-acc));
  } else if (idx < 16 * 4096 + 4096 * 128) {
    int i2 = idx - 16 * 4096;
    int n = i2 >> 7, cc = i2 & 127;
    float acc = 0.f;
#pragma unroll
    for (int j = 0; j < 3; ++j) {
      int c2 = cc - 1 + j;
      if (c2 >= 0 && c2 < 128) acc += k_c[j] * mean0[n * 128 + c2];
    }
    c_att[i2] = 1.f / (1.f + expf(-acc));
  }
}

// ---------------------------------------------------------------------------
// Phase C: attended = features * t_att * c_att (written out), then per-row
// LIF scan through W_p (spike-gather again), spike-count, and the final
// 20-class projection: out = (sum_t s_t / 16) @ W_out.T + b_out.
// ---------------------------------------------------------------------------
__global__ __launch_bounds__(128) void k_phaseC(
    const float* __restrict__ features, const float* __restrict__ t_att,
    const float* __restrict__ c_att, const float* __restrict__ WpT,
    const float* __restrict__ b_p, const float* __restrict__ W_out,
    const float* __restrict__ b_out, float* __restrict__ attended,
    float* __restrict__ out0) {
  const int n = blockIdx.x;
  const int c = threadIdx.x;
  const int wv = c >> 6, lane = c & 63;
  __shared__ float ca[128];
  __shared__ unsigned long long smask[2];
  __shared__ float g[128];
  ca[c] = c_att[n * 128 + c];
  float v3 = 0.f, ssum = 0.f;
  const float bpc = b_p[c];
  __syncthreads();
  for (int t = 0; t < 16; ++t) {
    float feat = features[(size_t)((t << 12) | n) * 128 + c];
    float ta = t_att[t * 4096 + n];
    float att = (feat * ta) * ca[c];        // matches reference mult order
    attended[(size_t)((t << 12) | n) * 128 + c] = att;
    bool act = feat >= 0.5f;
    __syncthreads();                        // previous iter done with smask
    unsigned long long bm = __ballot((int)act);
    if (lane == 0) smask[wv] = bm;
    __syncthreads();
    float h = bpc;
    unsigned long long m0 = smask[0], m1 = smask[1];
    while (m0) { int j = __builtin_ctzll(m0); m0 &= m0 - 1; h += (ta * ca[j]) * WpT[j * 128 + c]; }
    while (m1) { int j = __builtin_ctzll(m1); m1 &= m1 - 1; h += (ta * ca[64 + j]) * WpT[(64 + j) * 128 + c]; }
    v3 = v3 + (h - v3) * 0.5f;
    bool s = (v3 - 1.0f) >= 0.f;
    v3 = s ? 0.f : v3;
    ssum += s ? 1.f : 0.f;
  }
  g[c] = ssum * (1.f / 16.f);
  __syncthreads();
  if (c < 20) {
    float acc = b_out[c];
    for (int j = 0; j < 128; ++j) acc += g[j] * W_out[c * 128 + j];
    out0[n * 20 + c] = acc;
  }
}

// ---------------------------------------------------------------------------
extern "C" void kernel_launch(void* const* d_in, const int* in_sizes, int n_in,
                              void* d_out, int out_size, void* d_ws, size_t ws_size,
                              hipStream_t stream) {
  const float* x     = (const float*)d_in[0];
  const float* W_in  = (const float*)d_in[1];
  const float* b_in  = (const float*)d_in[2];
  const float* W_rec = (const float*)d_in[3];
  const float* b_rec = (const float*)d_in[4];
  const float* W2    = (const float*)d_in[5];
  const float* b2    = (const float*)d_in[6];
  const float* k_t   = (const float*)d_in[7];
  const float* k_c   = (const float*)d_in[8];
  const float* W_p   = (const float*)d_in[9];
  const float* b_p   = (const float*)d_in[10];
  const float* W_out = (const float*)d_in[11];
  const float* b_out = (const float*)d_in[12];

  float* out      = (float*)d_out;
  float* out0     = out;                        // [4096,20]
  float* features = out + 81920;                // [16,4096,128]
  float* attended = out + 81920 + 8388608;      // [16,4096,128]
  float* XW       = attended;                   // staged here, overwritten by phase C

  float* ws      = (float*)d_ws;
  float* WrT     = ws;                 // 16384
  float* W2T     = ws + 16384;         // 16384
  float* WpT     = ws + 32768;         // 16384
  float* mean_ch = ws + 49152;         // 16*4096
  float* mean0   = ws + 114688;        // 4096*128
  float* t_att   = ws + 638976;        // 16*4096
  float* c_att   = ws + 704512;        // 4096*128   (total 1228800 f32 ≈ 4.9 MB)

  hipLaunchKernelGGL(k_transpose, dim3(192), dim3(256), 0, stream,
                     W_rec, W2, W_p, WrT, W2T, WpT);
  hipLaunchKernelGGL(k_gemm_xw, dim3(512), dim3(256), 0, stream,
                     x, W_in, b_in, b_rec, XW);
  hipLaunchKernelGGL(k_phaseA, dim3(4096), dim3(128), 0, stream,
                     XW, WrT, W2T, b2, features, mean_ch, mean0);
  hipLaunchKernelGGL(k_atts, dim3((16 * 4096 + 4096 * 128) / 256), dim3(256), 0, stream,
                     mean_ch, mean0, k_t, k_c, t_att, c_att);
  hipLaunchKernelGGL(k_phaseC, dim3(4096), dim3(128), 0, stream,
                     features, t_att, c_att, WpT, b_p, W_out, b_out, attended, out0);
}

// Round 2
// 117.674 us; speedup vs baseline: 1.7824x; 1.7824x over previous
//
#include <hip/hip_runtime.h>
#include <hip/hip_bf16.h>
#include <stdint.h>

// Problem constants: N=4096, T=16, D=700 (pad 704), C=128, NC=20
// Output layout (f32): out0 [4096,20] | features [16,4096,128] | attended [16,4096,128]

typedef __attribute__((ext_vector_type(8))) short short8;  // bf16x8 MFMA frag
typedef __attribute__((ext_vector_type(4))) float f32x4;

#define MFMA16(a, b, c) __builtin_amdgcn_mfma_f32_16x16x32_bf16(a, b, c, 0, 0, 0)

__device__ inline void gload16(const void* g, void* l) {
  __builtin_amdgcn_global_load_lds(
      (const __attribute__((address_space(1))) uint32_t*)g,
      (__attribute__((address_space(3))) uint32_t*)l, 16, 0, 0);
}

// Exact 3-way bf16 split: v == hi + mid + lo (bitwise, 24 = 3x8 mantissa bits)
__device__ inline float bf_round(float v, short& bits) {
  __hip_bfloat16 b = __float2bfloat16(v);
  short s; __builtin_memcpy(&s, &b, 2);
  bits = s;
  unsigned int u = ((unsigned int)(unsigned short)s) << 16;
  return __uint_as_float(u);
}
__device__ inline void split1(float v, short& h, short& m, short& l) {
  float fh = bf_round(v, h);
  float r = v - fh;
  float fm = bf_round(r, m);
  float r2 = r - fm;  // <= 8 significant bits -> exact in bf16
  __hip_bfloat16 b = __float2bfloat16(r2);
  __builtin_memcpy(&l, &b, 2);
}

// ---------------------------------------------------------------------------
// Prep: split W_in [128][700] into 3 bf16 arrays [128][704] (k-padded zeros)
// ---------------------------------------------------------------------------
__global__ void k_split(const float* __restrict__ Win, ushort* __restrict__ B3) {
  int idx = blockIdx.x * blockDim.x + threadIdx.x;
  if (idx >= 128 * 704) return;
  int c = idx / 704, d = idx - c * 704;
  float v = (d < 700) ? Win[c * 700 + d] : 0.f;
  short h, m, l;
  split1(v, h, m, l);
  B3[idx] = (ushort)h;
  B3[90112 + idx] = (ushort)m;
  B3[180224 + idx] = (ushort)l;
}

// ---------------------------------------------------------------------------
// Transpose the three 128x128 weight matrices for the spike-gather phases
// ---------------------------------------------------------------------------
__global__ void k_transpose(const float* __restrict__ Wr, const float* __restrict__ W2,
                            const float* __restrict__ Wp, float* __restrict__ WrT,
                            float* __restrict__ W2T, float* __restrict__ WpT) {
  int idx = blockIdx.x * blockDim.x + threadIdx.x;
  if (idx >= 3 * 16384) return;
  int sel = idx >> 14;
  int r = idx & 16383;
  int j = r >> 7, c = r & 127;
  const float* src = (sel == 0) ? Wr : (sel == 1) ? W2 : Wp;
  float* dst = (sel == 0) ? WrT : (sel == 1) ? W2T : WpT;
  dst[r] = src[c * 128 + j];
}

// ---------------------------------------------------------------------------
// GEMM1 via split-bf16 6-product MFMA (fp32-grade accuracy):
//   XW[m][c] = x_row(m) . W_in[c] + b_in[c] + b_rec[c],  m = t*4096+n
// M=65536, K=704 (zero-padded), N=128. 128x128 tile, 512 blocks, 4 waves.
// A staged f32 via global_load_lds with XOR-swizzled source (G4 fix for
// 128B rows); B staged bf16 [n][k] (conflict-free). Double-buffered.
// ---------------------------------------------------------------------------
__global__ __launch_bounds__(256, 2) void k_gemm_mfma(
    const float* __restrict__ x, const ushort* __restrict__ Bs3,
    const float* __restrict__ b_in, const float* __restrict__ b_rec,
    float* __restrict__ XW) {
  __shared__ __align__(16) char lds[81920];  // A: 2x16K f32 | B: 2x24K bf16x3

  const int tid = threadIdx.x;
  const int w = tid >> 6;
  const int l = tid & 63;
  const int blk = blockIdx.x;

  // --- staging constants ---
  // A: 16 calls of 8 rows; wave w does calls w*4+i. lane: row +l>>3, chunk l&7.
  // Swizzle: LDS pos (m, p) must hold global chunk p ^ (m&7); m&7 == l>>3.
  const int jA = (((l & 7) ^ (l >> 3)) * 4);  // source k-offset (elements)
  const int t_blk = (blk * 128) >> 12;
  const int n0_blk = (blk * 128) & 4095;
  int arow[4];
#pragma unroll
  for (int i = 0; i < 4; ++i) {
    int m = (w * 4 + i) * 8 + (l >> 3);
    arow[i] = ((n0_blk + m) * 16 + t_blk) * 700;
  }
  // B: 24 calls (3 splits x 8 sub); wave w does idx=w*6+i. 16 rows/call.
  const ushort* bsrc[6];
  int bdst[6];
#pragma unroll
  for (int i = 0; i < 6; ++i) {
    int idx = w * 6 + i;
    int split = idx >> 3, sub = idx & 7;
    int n = sub * 16 + (l >> 2);
    bsrc[i] = Bs3 + split * 90112 + n * 704 + (l & 3) * 8;
    bdst[i] = 32768 + split * 8192 + sub * 1024;
  }
  const int adst = (w * 4) * 1024;

  // --- fragment read constants ---
  const int lm = l & 15, kh = l >> 4;
  const int p0 = ((2 * kh) ^ (lm & 7)) * 16;
  const int p1 = ((2 * kh + 1) ^ (lm & 7)) * 16;
  const int aoff0 = (w * 32 + lm) * 128;
  const int aoff1 = (w * 32 + 16 + lm) * 128;
  const int boff = 32768 + lm * 64 + kh * 16;

  f32x4 acc[2][8];
#pragma unroll
  for (int i = 0; i < 2; ++i)
#pragma unroll
    for (int j = 0; j < 8; ++j) acc[i][j] = (f32x4){0.f, 0.f, 0.f, 0.f};

  auto STAGE = [&](int buf, int kt) {
    const int k0 = kt * 32;
#pragma unroll
    for (int i = 0; i < 4; ++i) {
      int k = k0 + jA;
      int off = (k < 700) ? (arow[i] + k) : 0;  // pad region: B is zero there
      gload16(x + off, lds + adst + i * 1024 + buf * 16384);
    }
#pragma unroll
    for (int i = 0; i < 6; ++i)
      gload16(bsrc[i] + k0, lds + bdst[i] + buf * 24576);
  };

  STAGE(0, 0);
  __syncthreads();
  int buf = 0;
  for (int kt = 0; kt < 22; ++kt) {
    if (kt + 1 < 22) STAGE(buf ^ 1, kt + 1);
    const char* A = lds + buf * 16384;
    const char* B = lds + buf * 24576;
    short8 ah[2], am[2], al[2];
#pragma unroll
    for (int mf = 0; mf < 2; ++mf) {
      const char* ab = A + (mf ? aoff1 : aoff0);
      float4 q0 = *(const float4*)(ab + p0);
      float4 q1 = *(const float4*)(ab + p1);
      float f[8] = {q0.x, q0.y, q0.z, q0.w, q1.x, q1.y, q1.z, q1.w};
#pragma unroll
      for (int j = 0; j < 8; ++j) {
        short hh, mm, ll;
        split1(f[j], hh, mm, ll);
        ah[mf][j] = hh; am[mf][j] = mm; al[mf][j] = ll;
      }
    }
#pragma unroll
    for (int nf = 0; nf < 8; ++nf) {
      const char* bb = B + nf * 1024 + boff;
      short8 bh = *(const short8*)(bb);
      short8 bm = *(const short8*)(bb + 8192);
      short8 bl = *(const short8*)(bb + 16384);
#pragma unroll
      for (int mf = 0; mf < 2; ++mf) {
        acc[mf][nf] = MFMA16(ah[mf], bh, acc[mf][nf]);
        acc[mf][nf] = MFMA16(am[mf], bh, acc[mf][nf]);
        acc[mf][nf] = MFMA16(ah[mf], bm, acc[mf][nf]);
        acc[mf][nf] = MFMA16(am[mf], bm, acc[mf][nf]);
        acc[mf][nf] = MFMA16(al[mf], bh, acc[mf][nf]);
        acc[mf][nf] = MFMA16(ah[mf], bl, acc[mf][nf]);
      }
    }
    __syncthreads();
    buf ^= 1;
  }

  // Epilogue: C/D layout col=lane&15, row=(lane>>4)*4+r  (m89-verified)
  const int outbase = blk * 128;
#pragma unroll
  for (int nf = 0; nf < 8; ++nf) {
    int col = nf * 16 + lm;
    float bias = b_in[col] + b_rec[col];
#pragma unroll
    for (int mf = 0; mf < 2; ++mf) {
      int mrow = outbase + w * 32 + mf * 16 + kh * 4;
#pragma unroll
      for (int r = 0; r < 4; ++r)
        XW[(size_t)(mrow + r) * 128 + col] = acc[mf][nf][r] + bias;
    }
  }
}

// ---------------------------------------------------------------------------
// Phase A: per-row recurrent LIF scan over T=16 (ballot-mask spike gathers)
// ---------------------------------------------------------------------------
__global__ __launch_bounds__(128) void k_phaseA(
    const float* __restrict__ XW, const float* __restrict__ WrT,
    const float* __restrict__ W2T, const float* __restrict__ b2,
    float* __restrict__ features, float* __restrict__ mean_ch,
    float* __restrict__ mean0) {
  const int n = blockIdx.x;
  const int c = threadIdx.x;
  const int wv = c >> 6, lane = c & 63;
  __shared__ unsigned long long smask[2];
  __shared__ float red[2];
  if (c < 2) smask[c] = 0ull;
  float v1 = 0.f, v2 = 0.f, fsum = 0.f;
  const float b2c = b2[c];
  __syncthreads();
  for (int t = 0; t < 16; ++t) {
    float inp = XW[(size_t)((t << 12) | n) * 128 + c];
    unsigned long long p0 = smask[0], p1 = smask[1];
    while (p0) { int j = __builtin_ctzll(p0); p0 &= p0 - 1; inp += WrT[j * 128 + c]; }
    while (p1) { int j = __builtin_ctzll(p1); p1 &= p1 - 1; inp += WrT[(64 + j) * 128 + c]; }
    v1 = v1 + (inp - v1) * 0.5f;
    bool s1 = (v1 - 1.0f) >= 0.f;
    v1 = s1 ? 0.f : v1;
    __syncthreads();
    unsigned long long bm = __ballot((int)s1);
    if (lane == 0) smask[wv] = bm;
    __syncthreads();
    float x2 = b2c;
    unsigned long long q0 = smask[0], q1 = smask[1];
    while (q0) { int j = __builtin_ctzll(q0); q0 &= q0 - 1; x2 += W2T[j * 128 + c]; }
    while (q1) { int j = __builtin_ctzll(q1); q1 &= q1 - 1; x2 += W2T[(64 + j) * 128 + c]; }
    v2 = v2 + (x2 - v2) * 0.5f;
    bool f = (v2 - 1.0f) >= 0.f;
    v2 = f ? 0.f : v2;
    float ff = f ? 1.f : 0.f;
    features[(size_t)((t << 12) | n) * 128 + c] = ff;
    fsum += ff;
    float rs = ff;
    for (int off = 32; off > 0; off >>= 1) rs += __shfl_down(rs, off);
    if (lane == 0) red[wv] = rs;
    __syncthreads();
    if (c == 0) mean_ch[t * 4096 + n] = (red[0] + red[1]) * (1.f / 128.f);
  }
  mean0[n * 128 + c] = fsum * (1.f / 16.f);
}

// ---------------------------------------------------------------------------
// Attention maps: SAME-pad width-3 correlations + sigmoid
// ---------------------------------------------------------------------------
__global__ void k_atts(const float* __restrict__ mean_ch, const float* __restrict__ mean0,
                       const float* __restrict__ k_t, const float* __restrict__ k_c,
                       float* __restrict__ t_att, float* __restrict__ c_att) {
  int idx = blockIdx.x * blockDim.x + threadIdx.x;
  if (idx < 16 * 4096) {
    int ti = idx >> 12, n = idx & 4095;
    float acc = 0.f;
#pragma unroll
    for (int j = 0; j < 3; ++j) {
      int tt = ti - 1 + j;
      if (tt >= 0 && tt < 16) acc += k_t[j] * mean_ch[tt * 4096 + n];
    }
    t_att[idx] = 1.f / (1.f + expf(-acc));
  } else if (idx < 16 * 4096 + 4096 * 128) {
    int i2 = idx - 16 * 4096;
    int n = i2 >> 7, cc = i2 & 127;
    float acc = 0.f;
#pragma unroll
    for (int j = 0; j < 3; ++j) {
      int c2 = cc - 1 + j;
      if (c2 >= 0 && c2 < 128) acc += k_c[j] * mean0[n * 128 + c2];
    }
    c_att[i2] = 1.f / (1.f + expf(-acc));
  }
}

// ---------------------------------------------------------------------------
// Phase C: attended write + LIF through W_p + final 20-class projection
// ---------------------------------------------------------------------------
__global__ __launch_bounds__(128) void k_phaseC(
    const float* __restrict__ features, const float* __restrict__ t_att,
    const float* __restrict__ c_att, const float* __restrict__ WpT,
    const float* __restrict__ b_p, const float* __restrict__ W_out,
    const float* __restrict__ b_out, float* __restrict__ attended,
    float* __restrict__ out0) {
  const int n = blockIdx.x;
  const int c = threadIdx.x;
  const int wv = c >> 6, lane = c & 63;
  __shared__ float ca[128];
  __shared__ unsigned long long smask[2];
  __shared__ float g[128];
  ca[c] = c_att[n * 128 + c];
  float v3 = 0.f, ssum = 0.f;
  const float bpc = b_p[c];
  __syncthreads();
  for (int t = 0; t < 16; ++t) {
    float feat = features[(size_t)((t << 12) | n) * 128 + c];
    float ta = t_att[t * 4096 + n];
    float att = (feat * ta) * ca[c];
    attended[(size_t)((t << 12) | n) * 128 + c] = att;
    bool act = feat >= 0.5f;
    __syncthreads();
    unsigned long long bm = __ballot((int)act);
    if (lane == 0) smask[wv] = bm;
    __syncthreads();
    float h = bpc;
    unsigned long long m0 = smask[0], m1 = smask[1];
    while (m0) { int j = __builtin_ctzll(m0); m0 &= m0 - 1; h += (ta * ca[j]) * WpT[j * 128 + c]; }
    while (m1) { int j = __builtin_ctzll(m1); m1 &= m1 - 1; h += (ta * ca[64 + j]) * WpT[(64 + j) * 128 + c]; }
    v3 = v3 + (h - v3) * 0.5f;
    bool s = (v3 - 1.0f) >= 0.f;
    v3 = s ? 0.f : v3;
    ssum += s ? 1.f : 0.f;
  }
  g[c] = ssum * (1.f / 16.f);
  __syncthreads();
  if (c < 20) {
    float acc = b_out[c];
    for (int j = 0; j < 128; ++j) acc += g[j] * W_out[c * 128 + j];
    out0[n * 20 + c] = acc;
  }
}

// ---------------------------------------------------------------------------
extern "C" void kernel_launch(void* const* d_in, const int* in_sizes, int n_in,
                              void* d_out, int out_size, void* d_ws, size_t ws_size,
                              hipStream_t stream) {
  const float* x     = (const float*)d_in[0];
  const float* W_in  = (const float*)d_in[1];
  const float* b_in  = (const float*)d_in[2];
  const float* W_rec = (const float*)d_in[3];
  const float* b_rec = (const float*)d_in[4];
  const float* W2    = (const float*)d_in[5];
  const float* b2    = (const float*)d_in[6];
  const float* k_t   = (const float*)d_in[7];
  const float* k_c   = (const float*)d_in[8];
  const float* W_p   = (const float*)d_in[9];
  const float* b_p   = (const float*)d_in[10];
  const float* W_out = (const float*)d_in[11];
  const float* b_out = (const float*)d_in[12];

  float* out      = (float*)d_out;
  float* out0     = out;                        // [4096,20]
  float* features = out + 81920;                // [16,4096,128]
  float* attended = out + 81920 + 8388608;      // [16,4096,128]
  float* XW       = attended;                   // staged here, overwritten by phase C

  float* ws      = (float*)d_ws;
  float* WrT     = ws;                 // 16384
  float* W2T     = ws + 16384;         // 16384
  float* WpT     = ws + 32768;         // 16384
  // B-splits live only during the GEMM; the same region is reused afterwards
  // by mean_ch/mean0 (written by phaseA).
  ushort* B3     = (ushort*)(ws + 49152);  // 3 x 128 x 704 bf16 = 540 KB
  float* mean_ch = ws + 49152;         // 16*4096
  float* mean0   = ws + 114688;        // 4096*128
  float* t_att   = ws + 638976;        // 16*4096
  float* c_att   = ws + 704512;        // 4096*128

  hipLaunchKernelGGL(k_transpose, dim3(192), dim3(256), 0, stream,
                     W_rec, W2, W_p, WrT, W2T, WpT);
  hipLaunchKernelGGL(k_split, dim3(352), dim3(256), 0, stream, W_in, B3);
  hipLaunchKernelGGL(k_gemm_mfma, dim3(512), dim3(256), 0, stream,
                     x, B3, b_in, b_rec, XW);
  hipLaunchKernelGGL(k_phaseA, dim3(4096), dim3(128), 0, stream,
                     XW, WrT, W2T, b2, features, mean_ch, mean0);
  hipLaunchKernelGGL(k_atts, dim3((16 * 4096 + 4096 * 128) / 256), dim3(256), 0, stream,
                     mean_ch, mean0, k_t, k_c, t_att, c_att);
  hipLaunchKernelGGL(k_phaseC, dim3(4096), dim3(128), 0, stream,
                     features, t_att, c_att, WpT, b_p, W_out, b_out, attended, out0);
}

// Round 3
// 99.520 us; speedup vs baseline: 2.1075x; 1.1824x over previous
//
#include <hip/hip_runtime.h>
#include <hip/hip_bf16.h>
#include <stdint.h>

// Problem constants: N=4096, T=16, D=700 (pad 704), C=128, NC=20
// Output layout (f32): out0 [4096,20] | features [16,4096,128] | attended [16,4096,128]

typedef __attribute__((ext_vector_type(8))) short short8;  // bf16x8 MFMA frag
typedef __attribute__((ext_vector_type(4))) float f32x4;
typedef unsigned long long u64;

#define MFMA16(a, b, c) __builtin_amdgcn_mfma_f32_16x16x32_bf16(a, b, c, 0, 0, 0)

__device__ inline void gload16(const void* g, void* l) {
  __builtin_amdgcn_global_load_lds(
      (const __attribute__((address_space(1))) uint32_t*)g,
      (__attribute__((address_space(3))) uint32_t*)l, 16, 0, 0);
}

// Exact 3-way bf16 split: v == hi + mid + lo (bitwise, 24 = 3x8 mantissa bits)
__device__ inline float bf_round(float v, short& bits) {
  __hip_bfloat16 b = __float2bfloat16(v);
  short s; __builtin_memcpy(&s, &b, 2);
  bits = s;
  unsigned int u = ((unsigned int)(unsigned short)s) << 16;
  return __uint_as_float(u);
}
__device__ inline void split1(float v, short& h, short& m, short& l) {
  float fh = bf_round(v, h);
  float r = v - fh;
  float fm = bf_round(r, m);
  float r2 = r - fm;  // <= 8 significant bits -> exact in bf16
  __hip_bfloat16 b = __float2bfloat16(r2);
  __builtin_memcpy(&l, &b, 2);
}

// ---------------------------------------------------------------------------
// Prep (one launch): transpose WrT/W2T/WpT + split W_in into 3 bf16 planes
// ---------------------------------------------------------------------------
__global__ void k_prep(const float* __restrict__ Wr, const float* __restrict__ W2,
                       const float* __restrict__ Wp, const float* __restrict__ Win,
                       float* __restrict__ WrT, float* __restrict__ W2T,
                       float* __restrict__ WpT, ushort* __restrict__ B3) {
  int idx = blockIdx.x * blockDim.x + threadIdx.x;
  if (idx < 3 * 16384) {
    int sel = idx >> 14;
    int r = idx & 16383;
    int j = r >> 7, c = r & 127;
    const float* src = (sel == 0) ? Wr : (sel == 1) ? W2 : Wp;
    float* dst = (sel == 0) ? WrT : (sel == 1) ? W2T : WpT;
    dst[r] = src[c * 128 + j];
  } else {
    int i2 = idx - 49152;
    if (i2 >= 128 * 704) return;
    int c = i2 / 704, d = i2 - c * 704;
    float v = (d < 700) ? Win[c * 700 + d] : 0.f;
    short h, m, l;
    split1(v, h, m, l);
    B3[i2] = (ushort)h;
    B3[90112 + i2] = (ushort)m;
    B3[180224 + i2] = (ushort)l;
  }
}

// ---------------------------------------------------------------------------
// GEMM1 via split-bf16 6-product MFMA (fp32-grade accuracy):
//   XW[m][c] = x_row(m) . W_in[c] + b_in[c] + b_rec[c],  m = t*4096+n
// 128x128 tile, 512 blocks x 512 threads (8 waves, wave owns 16 rows).
// A staged f32 via global_load_lds w/ XOR-swizzled source; B staged bf16.
// Double-buffered (80 KB LDS -> 2 blocks/CU, 4 waves/SIMD).
// ---------------------------------------------------------------------------
__global__ __launch_bounds__(512, 4) void k_gemm_mfma(
    const float* __restrict__ x, const ushort* __restrict__ Bs3,
    const float* __restrict__ b_in, const float* __restrict__ b_rec,
    float* __restrict__ XW) {
  __shared__ __align__(16) char lds[81920];  // A: 2x16K f32 | B: 2x24K bf16x3

  const int tid = threadIdx.x;
  const int w = tid >> 6;      // 0..7
  const int l = tid & 63;
  const int blk = blockIdx.x;

  // --- staging constants ---
  // A: 16 calls of 8 rows; wave w does calls w*2+i (i=0,1). lane: row l>>3,
  // 16B chunk l&7. Swizzle: LDS (row, p) holds global chunk p ^ (row&7).
  const int jA = (((l & 7) ^ (l >> 3)) * 4);  // source k-offset (elements)
  const int t_blk = (blk * 128) >> 12;
  const int n0_blk = (blk * 128) & 4095;
  int arow[2];
#pragma unroll
  for (int i = 0; i < 2; ++i) {
    int m = (w * 2 + i) * 8 + (l >> 3);
    arow[i] = ((n0_blk + m) * 16 + t_blk) * 700;
  }
  // B: 24 calls (3 splits x 8 sub); wave w does idx=w*3+i (i=0..2). 16 rows/call.
  const ushort* bsrc[3];
  int bdst[3];
#pragma unroll
  for (int i = 0; i < 3; ++i) {
    int idx = w * 3 + i;
    int split = idx >> 3, sub = idx & 7;
    int n = sub * 16 + (l >> 2);
    bsrc[i] = Bs3 + split * 90112 + n * 704 + (l & 3) * 8;
    bdst[i] = 32768 + split * 8192 + sub * 1024;
  }
  const int adst = (w * 2) * 1024;

  // --- fragment read constants ---
  const int lm = l & 15, kh = l >> 4;
  const int p0 = ((2 * kh) ^ (lm & 7)) * 16;
  const int p1 = ((2 * kh + 1) ^ (lm & 7)) * 16;
  const int aoff = (w * 16 + lm) * 128;   // wave owns rows w*16..w*16+15
  const int boff = 32768 + lm * 64 + kh * 16;

  f32x4 acc[8];
#pragma unroll
  for (int j = 0; j < 8; ++j) acc[j] = (f32x4){0.f, 0.f, 0.f, 0.f};

  auto STAGE = [&](int buf, int kt) {
    const int k0 = kt * 32;
#pragma unroll
    for (int i = 0; i < 2; ++i) {
      int k = k0 + jA;
      int off = (k < 700) ? (arow[i] + k) : 0;  // pad region: B is zero there
      gload16(x + off, lds + adst + i * 1024 + buf * 16384);
    }
#pragma unroll
    for (int i = 0; i < 3; ++i)
      gload16(bsrc[i] + k0, lds + bdst[i] + buf * 24576);
  };

  STAGE(0, 0);
  __syncthreads();
  int buf = 0;
  for (int kt = 0; kt < 22; ++kt) {
    if (kt + 1 < 22) STAGE(buf ^ 1, kt + 1);
    const char* A = lds + buf * 16384;
    const char* B = lds + buf * 24576;
    short8 ah, am, al;
    {
      const char* ab = A + aoff;
      float4 q0 = *(const float4*)(ab + p0);
      float4 q1 = *(const float4*)(ab + p1);
      float f[8] = {q0.x, q0.y, q0.z, q0.w, q1.x, q1.y, q1.z, q1.w};
#pragma unroll
      for (int j = 0; j < 8; ++j) {
        short hh, mm, ll;
        split1(f[j], hh, mm, ll);
        ah[j] = hh; am[j] = mm; al[j] = ll;
      }
    }
#pragma unroll
    for (int nf = 0; nf < 8; ++nf) {
      const char* bb = B + nf * 1024 + boff;
      short8 bh = *(const short8*)(bb);
      short8 bm = *(const short8*)(bb + 8192);
      short8 bl = *(const short8*)(bb + 16384);
      acc[nf] = MFMA16(ah, bh, acc[nf]);
      acc[nf] = MFMA16(am, bh, acc[nf]);
      acc[nf] = MFMA16(ah, bm, acc[nf]);
      acc[nf] = MFMA16(am, bm, acc[nf]);
      acc[nf] = MFMA16(al, bh, acc[nf]);
      acc[nf] = MFMA16(ah, bl, acc[nf]);
    }
    __syncthreads();
    buf ^= 1;
  }

  // Epilogue: C/D layout col=lane&15, row=(lane>>4)*4+r  (m89-verified)
  const int outbase = blk * 128;
#pragma unroll
  for (int nf = 0; nf < 8; ++nf) {
    int col = nf * 16 + lm;
    float bias = b_in[col] + b_rec[col];
    int mrow = outbase + w * 16 + kh * 4;
#pragma unroll
    for (int r = 0; r < 4; ++r)
      XW[(size_t)(mrow + r) * 128 + col] = acc[nf][r] + bias;
  }
}

// ---------------------------------------------------------------------------
// Fused scan: LIF layer1+2 (recurrent), attention maps, attended, LIF layer3,
// and the 20-class projection. Block = 2 rows x 128 channels. Features kept
// in LDS as bitmasks; channel-means are exact popcounts.
// ---------------------------------------------------------------------------
__global__ __launch_bounds__(256) void k_scan(
    const float* __restrict__ XW, const float* __restrict__ WrT,
    const float* __restrict__ W2T, const float* __restrict__ b2,
    const float* __restrict__ WpT, const float* __restrict__ b_p,
    const float* __restrict__ W_out, const float* __restrict__ b_out,
    const float* __restrict__ k_t, const float* __restrict__ k_c,
    float* __restrict__ features, float* __restrict__ attended,
    float* __restrict__ out0) {
  const int tid = threadIdx.x;
  const int r = tid >> 7;          // row within block
  const int c = tid & 127;         // channel
  const int n = blockIdx.x * 2 + r;
  const int wv = c >> 6;           // wave-half within row
  const int lane = tid & 63;

  __shared__ u64 smask[2][2];
  __shared__ u64 fmask[2][16][2];
  __shared__ float m0p[2][130];    // mean0 padded for c_att conv
  __shared__ float ta[2][16];
  __shared__ float ca[2][128];
  __shared__ float g[2][128];

  if (tid < 4) ((u64*)smask)[tid] = 0ull;
  float v1 = 0.f, v2 = 0.f, fsum = 0.f;
  const float b2c = b2[c];
  __syncthreads();

  // ---- phase 1: recurrent LIF scan ----
  for (int t = 0; t < 16; ++t) {
    float inp = XW[(size_t)((t << 12) | n) * 128 + c];
    u64 p0 = smask[r][0], p1 = smask[r][1];   // spikes_last (uniform per row)
    while (p0) { int j = __builtin_ctzll(p0); p0 &= p0 - 1; inp += WrT[j * 128 + c]; }
    while (p1) { int j = __builtin_ctzll(p1); p1 &= p1 - 1; inp += WrT[(64 + j) * 128 + c]; }
    v1 = v1 + (inp - v1) * 0.5f;            // decay_input=True, TAU=2
    bool s1 = (v1 - 1.0f) >= 0.f;
    v1 = s1 ? 0.f : v1;
    __syncthreads();                        // everyone done reading old smask
    u64 bm = __ballot((int)s1);
    if (lane == 0) smask[r][wv] = bm;
    __syncthreads();
    float x2 = b2c;
    u64 q0 = smask[r][0], q1 = smask[r][1];
    while (q0) { int j = __builtin_ctzll(q0); q0 &= q0 - 1; x2 += W2T[j * 128 + c]; }
    while (q1) { int j = __builtin_ctzll(q1); q1 &= q1 - 1; x2 += W2T[(64 + j) * 128 + c]; }
    v2 = v2 + (x2 - v2) * 0.5f;
    bool f = (v2 - 1.0f) >= 0.f;
    v2 = f ? 0.f : v2;
    float ff = f ? 1.f : 0.f;
    features[(size_t)((t << 12) | n) * 128 + c] = ff;
    fsum += ff;
    u64 fb = __ballot((int)f);
    if (lane == 0) fmask[r][t][wv] = fb;
  }

  // mean0 (exact: integer sums, pow2 divides)
  m0p[r][c + 1] = fsum * (1.f / 16.f);
  if (c == 0) { m0p[r][0] = 0.f; m0p[r][129] = 0.f; }
  __syncthreads();  // fmask + m0p complete

  // t_att: conv over T (SAME, width 3) of channel-means, + sigmoid
  if (c < 16) {
    float acc = 0.f;
#pragma unroll
    for (int j = 0; j < 3; ++j) {
      int tt = c - 1 + j;
      if (tt >= 0 && tt < 16) {
        float m = (float)(__popcll(fmask[r][tt][0]) + __popcll(fmask[r][tt][1])) * (1.f / 128.f);
        acc += k_t[j] * m;
      }
    }
    ta[r][c] = 1.f / (1.f + expf(-acc));
  }
  // c_att: conv over C (SAME, width 3) of time-means, + sigmoid
  {
    float acc = k_c[0] * m0p[r][c] + k_c[1] * m0p[r][c + 1] + k_c[2] * m0p[r][c + 2];
    ca[r][c] = 1.f / (1.f + expf(-acc));
  }
  __syncthreads();

  // ---- phase 2: attended + LIF layer3 + spike-count (no syncs needed) ----
  float v3 = 0.f, ssum = 0.f;
  const float bpc = b_p[c];
  const float cac = ca[r][c];
  for (int t = 0; t < 16; ++t) {
    u64 m0 = fmask[r][t][0], m1 = fmask[r][t][1];
    float tat = ta[r][t];
    bool bit = ((wv ? m1 : m0) >> (c & 63)) & 1;
    float att = bit ? tat * cac : 0.f;      // feat in {0,1}: (feat*ta)*ca
    attended[(size_t)((t << 12) | n) * 128 + c] = att;
    float h = bpc;
    while (m0) { int j = __builtin_ctzll(m0); m0 &= m0 - 1; h += (tat * ca[r][j]) * WpT[j * 128 + c]; }
    while (m1) { int j = __builtin_ctzll(m1); m1 &= m1 - 1; h += (tat * ca[r][64 + j]) * WpT[(64 + j) * 128 + c]; }
    v3 = v3 + (h - v3) * 0.5f;
    bool s = (v3 - 1.0f) >= 0.f;
    v3 = s ? 0.f : v3;
    ssum += s ? 1.f : 0.f;
  }
  g[r][c] = ssum * (1.f / 16.f);
  __syncthreads();
  if (c < 20) {
    float acc = b_out[c];
    for (int j = 0; j < 128; ++j) acc += g[r][j] * W_out[c * 128 + j];
    out0[n * 20 + c] = acc;
  }
}

// ---------------------------------------------------------------------------
extern "C" void kernel_launch(void* const* d_in, const int* in_sizes, int n_in,
                              void* d_out, int out_size, void* d_ws, size_t ws_size,
                              hipStream_t stream) {
  const float* x     = (const float*)d_in[0];
  const float* W_in  = (const float*)d_in[1];
  const float* b_in  = (const float*)d_in[2];
  const float* W_rec = (const float*)d_in[3];
  const float* b_rec = (const float*)d_in[4];
  const float* W2    = (const float*)d_in[5];
  const float* b2    = (const float*)d_in[6];
  const float* k_t   = (const float*)d_in[7];
  const float* k_c   = (const float*)d_in[8];
  const float* W_p   = (const float*)d_in[9];
  const float* b_p   = (const float*)d_in[10];
  const float* W_out = (const float*)d_in[11];
  const float* b_out = (const float*)d_in[12];

  float* out      = (float*)d_out;
  float* out0     = out;                        // [4096,20]
  float* features = out + 81920;                // [16,4096,128]
  float* attended = out + 81920 + 8388608;      // [16,4096,128]
  float* XW       = attended;                   // staged here, overwritten by scan

  float* ws  = (float*)d_ws;
  float* WrT = ws;                  // 16384 f32
  float* W2T = ws + 16384;          // 16384 f32
  float* WpT = ws + 32768;          // 16384 f32
  ushort* B3 = (ushort*)(ws + 49152);  // 3 x 128 x 704 bf16 = 540 KB

  hipLaunchKernelGGL(k_prep, dim3(544), dim3(256), 0, stream,
                     W_rec, W2, W_p, W_in, WrT, W2T, WpT, B3);
  hipLaunchKernelGGL(k_gemm_mfma, dim3(512), dim3(512), 0, stream,
                     x, B3, b_in, b_rec, XW);
  hipLaunchKernelGGL(k_scan, dim3(2048), dim3(256), 0, stream,
                     XW, WrT, W2T, b2, WpT, b_p, W_out, b_out, k_t, k_c,
                     features, attended, out0);
}